// Round 14
// baseline (538.263 us; speedup 1.0000x reference)
//
#include <hip/hip_runtime.h>
#include <hip/hip_bf16.h>
#include <math.h>

#define NPOS 16384   // B*H*W = 16*32*32
#define DD   512
#define PP   ((size_t)NPOS * DD)   // 8388608 elements per plane

typedef __bf16 bf16x8 __attribute__((ext_vector_type(8)));
typedef float  f32x4  __attribute__((ext_vector_type(4)));

// ---- async global->LDS, 16B per lane (global_load_lds_dwordx4) ----
__device__ __forceinline__ void gload16(const __bf16* g, __bf16* l) {
  __builtin_amdgcn_global_load_lds((__attribute__((address_space(1))) void*)(g),
                                   (__attribute__((address_space(3))) void*)(l), 16, 0, 0);
}
__device__ __forceinline__ void wait_vm0() { asm volatile("s_waitcnt vmcnt(0)" ::: "memory"); }
__device__ __forceinline__ void wait_vm2() { asm volatile("s_waitcnt vmcnt(2)" ::: "memory"); }
__device__ __forceinline__ void wait_lgkm0() { asm volatile("s_waitcnt lgkmcnt(0)" ::: "memory"); }

// ================= bf16 MFMA GEMM, 128x128 / 8 waves / 3-deep gload_lds ring =================
// R5-exact (measured optimum of the design space; ledger: B-direct ✗✗, 256^2 ✗,
// 128x256 ✗, ring-2 ~). 128x128 tile, 512 thr (8 waves 2Mx4N, wave 64x32, acc[4][2]);
// A+B via global_load_lds 16B 3-deep ring (48KB), counted s_waitcnt vmcnt(2) at tile
// end (never drains mid-loop); global-side XOR swizzle -> conflict-free frag reads
// (rule 21); s_setprio around MFMA; ONE barrier per K-tile; bijective XCD swizzle.
// epi 0: C0 fp32 (ld N) = acc + bias
// epi 1: N=1024; bn<512 -> C1b bf16 (ld 512); bn>=512 -> sigmoid -> C1 bf16 (ld 512)
//        (full-line bf16 epilogue via per-wave LDS shuffle, 64 rows x 80B)
// epi 2: C0 fp32 (ld N) = acc + bias + res
__global__ __launch_bounds__(512, 4) void gemm_k(
    const __bf16* __restrict__ A, const __bf16* __restrict__ Bt,
    const float* __restrict__ bias, const float* __restrict__ res,
    float* __restrict__ C0, __bf16* __restrict__ C1, __bf16* __restrict__ C1b,
    int N, int K, int epi)
{
  __shared__ __bf16 SM[3 * 4096 * 2];   // 48 KB: A ring [3][4096] then B ring [3][4096]
  __bf16 (*Asm)[4096] = (__bf16(*)[4096])SM;
  __bf16 (*Bsm)[4096] = (__bf16(*)[4096])(SM + 3 * 4096);

  const int tid  = threadIdx.x;
  const int w    = tid >> 6;
  const int lane = tid & 63;
  const int quad = lane >> 4;
  const int l16  = lane & 15;
  const int wm   = (w >> 2) << 6;       // 2 M-waves x 64 rows
  const int wn   = (w & 3) << 5;        // 4 N-waves x 32 cols

  // grid decode: bijective XCD swizzle, then ntc fastest (A-sharers adjacent per XCD)
  const int nwg = gridDim.x;
  const int cpx = nwg >> 3;
  const int lin = (blockIdx.x & 7) * cpx + (blockIdx.x >> 3);
  const int nbn = N >> 7;               // 128-wide N tiles (4 or 8)
  const int sh  = (nbn == 8) ? 3 : 2;
  const int mt  = lin >> sh;
  const int ntc = lin & (nbn - 1);
  const int bm  = mt << 7;
  const int bn  = ntc << 7;

  const __bf16* Ab = A  + (size_t)bm * K;
  const __bf16* Bb = Bt + (size_t)bn * K;
  const int nk = K >> 5;

  f32x4 acc[4][2];
  #pragma unroll
  for (int i = 0; i < 4; ++i)
    #pragma unroll
    for (int j = 0; j < 2; ++j) acc[i][j] = (f32x4){0.f, 0.f, 0.f, 0.f};

  // staging: 512 threads x 16B = one 128x32 tile per instruction. LDS lane-linear
  // (gload_lds requirement); global col-chunk pre-swizzled so swizzled frag reads see
  // linear data (rule 21): LDS[r][sl] = G[r][sl ^ ((r>>1)&3)].
  #define STG(P, gb, tile, buf) {                                               \
    const int r_ = tid >> 2, c_ = tid & 3;                                      \
    gload16(gb + (size_t)r_ * K + ((tile) << 5) + ((c_ ^ ((r_ >> 1) & 3)) << 3),\
            &P[buf][tid << 3]);                                                 \
  }

  // prologue: stage tiles 0,1 (4 loads); vmcnt(2) leaves tile1's 2 in flight
  STG(Asm, Ab, 0, 0) STG(Bsm, Bb, 0, 0)
  STG(Asm, Ab, 1, 1) STG(Bsm, Bb, 1, 1)
  wait_vm2();
  __builtin_amdgcn_s_barrier();

  int cur = 0;
  for (int t = 0; t < nk; ++t) {
    const int nx2 = (cur == 0) ? 2 : cur - 1;    // (cur+2)%3 : buffer for tile t+2
    const bool st = (t + 2 < nk);

    if (st) {
      STG(Asm, Ab, t + 2, nx2)
      STG(Bsm, Bb, t + 2, nx2)
    }

    bf16x8 af[4], bfr[2];
    #pragma unroll
    for (int i = 0; i < 4; ++i) {
      const int m = wm + i * 16 + l16;
      af[i] = *(const bf16x8*)(&Asm[cur][m * 32 + ((quad ^ ((m >> 1) & 3)) << 3)]);
    }
    #pragma unroll
    for (int j = 0; j < 2; ++j) {
      const int n = wn + j * 16 + l16;
      bfr[j] = *(const bf16x8*)(&Bsm[cur][n * 32 + ((quad ^ ((n >> 1) & 3)) << 3)]);
    }

    __builtin_amdgcn_s_setprio(1);
    #pragma unroll
    for (int i = 0; i < 4; ++i) {
      acc[i][0] = __builtin_amdgcn_mfma_f32_16x16x32_bf16(af[i], bfr[0], acc[i][0], 0, 0, 0);
      acc[i][1] = __builtin_amdgcn_mfma_f32_16x16x32_bf16(af[i], bfr[1], acc[i][1], 0, 0, 0);
    }
    __builtin_amdgcn_s_setprio(0);

    if (st) { wait_vm2(); } else { wait_vm0(); }
    __builtin_amdgcn_s_barrier();
    cur = (cur == 2) ? 0 : cur + 1;
  }
  #undef STG

  // ---- epilogue. C/D layout: col = lane&15, row = quad*4 + reg  [m89-verified] ----
  if (epi == 1) {
    const bool dosig = (bn >= 512);
    __bf16* dst = dosig ? C1 : C1b;
    const int cb = dosig ? (bn - 512) : bn;
    char* wb = (char*)SM + w * 5120;             // 8 waves x 5120 B = 40 KB <= 48 KB
    #pragma unroll
    for (int i = 0; i < 4; ++i)
      #pragma unroll
      for (int j = 0; j < 2; ++j) {
        const float bv = bias[bn + wn + j * 16 + l16];
        #pragma unroll
        for (int r = 0; r < 4; ++r) {
          float v = acc[i][j][r] + bv;
          if (dosig) v = 1.f / (1.f + expf(-v));
          *(__bf16*)(wb + (i * 16 + quad * 4 + r) * 80 + (j * 16 + l16) * 2) = (__bf16)v;
        }
      }
    wait_lgkm0();                                 // wave-local; no barrier needed
    #pragma unroll
    for (int s = 0; s < 4; ++s) {
      const int rr = s * 16 + (lane >> 2);        // 0..63 within wave tile
      bf16x8 vv = *(bf16x8*)(wb + rr * 80 + (lane & 3) * 16);
      const int grow = bm + wm + rr;
      *(bf16x8*)(dst + (size_t)grow * 512 + cb + wn + (lane & 3) * 8) = vv;
    }
  } else {
    #pragma unroll
    for (int j = 0; j < 2; ++j) {
      const int col = wn + j * 16 + l16;
      const float bv = bias[bn + col];
      #pragma unroll
      for (int i = 0; i < 4; ++i) {
        const int row0 = bm + wm + i * 16 + quad * 4;
        #pragma unroll
        for (int r = 0; r < 4; ++r) {
          float v = acc[i][j][r] + bv;
          size_t off = (size_t)(row0 + r) * N + bn + col;
          if (epi == 2) v += res[off];
          C0[off] = v;
        }
      }
    }
  }
}

// ================= fused preamble: tokens cvt + 3 weight transposes (R11-proven) =================
__global__ __launch_bounds__(256) void prep_k(
    const float* __restrict__ tokens, __bf16* __restrict__ tb16,
    const float* __restrict__ in_w, __bf16* __restrict__ inwT,
    const float* __restrict__ iw,  __bf16* __restrict__ iwT,
    const float* __restrict__ ow,  __bf16* __restrict__ owT)
{
  __shared__ float t[32][33];
  const int bx = blockIdx.x;
  if (bx < 6144) {
    size_t i = ((size_t)bx * 256 + threadIdx.x) * 8;
    float4 a = *(const float4*)(tokens + i);
    float4 b = *(const float4*)(tokens + i + 4);
    bf16x8 v;
    v[0] = (__bf16)a.x; v[1] = (__bf16)a.y; v[2] = (__bf16)a.z; v[3] = (__bf16)a.w;
    v[4] = (__bf16)b.x; v[5] = (__bf16)b.y; v[6] = (__bf16)b.z; v[7] = (__bf16)b.w;
    *(bf16x8*)(tb16 + i) = v;
    return;
  }
  int K, N, xb, yb, zb;
  const float* s;
  __bf16* d;
  size_t sstr, dstr;
  int b2 = bx - 6144;
  if (b2 < 384) {            // in_w: 768x512, tiles 16(N) x 24(K)
    K = 768; N = 512; xb = b2 & 15; yb = b2 >> 4; zb = 0;
    s = in_w; d = inwT; sstr = 0; dstr = 0;
  } else if ((b2 -= 384) < 2048) {   // iw: 4 x 512x1024, tiles 32(N) x 16(K) x 4
    K = 512; N = 1024; xb = b2 & 31; yb = (b2 >> 5) & 15; zb = b2 >> 9;
    s = iw; d = iwT; sstr = (size_t)512 * 1024; dstr = (size_t)1024 * 512;
  } else {                   // ow: 4 x 512x512, tiles 16(N) x 16(K) x 4
    b2 -= 2048;
    K = 512; N = 512; xb = b2 & 15; yb = (b2 >> 4) & 15; zb = b2 >> 8;
    s = ow; d = owT; sstr = (size_t)512 * 512; dstr = (size_t)512 * 512;
  }
  s += zb * sstr;
  d += zb * dstr;
  const int n0 = xb * 32, k0 = yb * 32;
  const int tx = threadIdx.x & 31, ty = threadIdx.x >> 5;   // 32x8
  #pragma unroll
  for (int i = 0; i < 4; ++i)
    t[ty + i * 8][tx] = s[(size_t)(k0 + ty + i * 8) * N + n0 + tx];
  __syncthreads();
  #pragma unroll
  for (int i = 0; i < 4; ++i)
    d[(size_t)(n0 + ty + i * 8) * K + k0 + tx] = (__bf16)t[tx][ty + i * 8];
}

// ---------------- LayerNorm over D=512, one wave per position, bf16 out ----------------
__global__ __launch_bounds__(256) void ln_k(const float* __restrict__ x, const float* __restrict__ w,
                                            const float* __restrict__ bv, __bf16* __restrict__ out)
{
  int gw = (blockIdx.x * 256 + threadIdx.x) >> 6;   // position
  int lane = threadIdx.x & 63;
  const float* xp = x + ((size_t)gw << 9) + lane * 8;
  float4 u0 = *(const float4*)xp;
  float4 u1 = *(const float4*)(xp + 4);
  float v[8] = {u0.x,u0.y,u0.z,u0.w,u1.x,u1.y,u1.z,u1.w};
  float s = 0.f;
  #pragma unroll
  for (int j = 0; j < 8; ++j) s += v[j];
  #pragma unroll
  for (int off = 32; off; off >>= 1) s += __shfl_xor(s, off, 64);
  float mu = s * (1.f/512.f);
  float q = 0.f;
  #pragma unroll
  for (int j = 0; j < 8; ++j) { float d = v[j] - mu; q += d*d; }
  #pragma unroll
  for (int off = 32; off; off >>= 1) q += __shfl_xor(q, off, 64);
  float rstd = rsqrtf(q * (1.f/512.f) + 1e-5f);
  int dch = lane * 8;
  float4 w0 = *(const float4*)(w + dch),  w1 = *(const float4*)(w + dch + 4);
  float4 b0 = *(const float4*)(bv + dch), b1 = *(const float4*)(bv + dch + 4);
  float wv[8] = {w0.x,w0.y,w0.z,w0.w,w1.x,w1.y,w1.z,w1.w};
  float bb[8] = {b0.x,b0.y,b0.z,b0.w,b1.x,b1.y,b1.z,b1.w};
  bf16x8 ov;
  #pragma unroll
  for (int j = 0; j < 8; ++j) ov[j] = (__bf16)((v[j] - mu) * rstd * wv[j] + bb[j]);
  *(bf16x8*)(out + ((size_t)gw << 9) + dch) = ov;
}

// ================= Fully-fused conv + 2D scan, 8 ch/block, 4 blocks/CU (R12) =================
// R12: R3->R4 mechanism extended (more independent barrier groups at equal waves/CU):
// 16->8 ch/block. 256 thr (32 chunks x 8 ch), LDS 39KB (T/Y 17.5KB each + S 4KB) ->
// 4 blocks/CU x 4 waves = 16 waves/CU (same as R4) but 4 barrier groups (was 2).
// Grid 64 cg x 16 b = 1024 blocks = 4/CU exact, no tail.
// CST8 = 280 elem (560B = 140dw === 12 mod 32): row-scan reads place the 8 c0-groups
// on disjoint bank quads -> conflict-free (272 would 4-way alias); col reads are
// 128B contiguous -> free. XCD swizzle cg = (bx&7)*8 + bx>>3: the 8 cgs sharing each
// 128B global line land on one XCD -> L2 merges 16B segments (FETCH/WRITE stay ideal).
__device__ __forceinline__ float sig_a(float al) {
  float a = 1.f / (1.f + expf(-al));
  return fminf(fmaxf(a, 1e-4f), 1.f - 1e-4f);
}

#define CST8 280   // chunk stride in elements: 32*8 + 24 pad (560 B)

__global__ __launch_bounds__(256, 4) void scan2d_k(
    const __bf16* __restrict__ xin, const float* __restrict__ cw, const float* __restrict__ cb,
    const float* __restrict__ alog, const float* __restrict__ bvec, const float* __restrict__ cvec,
    const float* __restrict__ dvec, const __bf16* __restrict__ gate, __bf16* __restrict__ yo)
{
  __shared__ __bf16 T[32 * CST8];   // xin tile; partial park in phase C. 17.5 KB
  __shared__ __bf16 Y[32 * CST8];   // u tile. 17.5 KB
  __shared__ float  S[4][32][8];    // chunk sums: rowF,rowB,colF,colB. 4 KB
  const int tid = threadIdx.x;
  const int bx  = blockIdx.x;
  const int cg  = ((bx & 7) << 3) | (bx >> 3);   // channel group of 8; line-mates same XCD
  const int b   = blockIdx.y;
  const int ch  = tid & 7;
  const int c0  = tid >> 3;         // 0..31; thread owns chunk (row) c0
  const int d   = (cg << 3) + ch;

  const float a   = sig_a(alog[d]);
  const float lna = logf(a);
  const float ia  = 1.f / a;
  const float bb  = bvec[d];
  const float sc  = 0.25f * cvec[d];
  const float dd  = dvec[d];

  const __bf16* ub = xin + ((size_t)b << 19) + (cg << 3);

  // ---- load xin tile: 4 x bf16x8 per thread (one full 8-ch position row each) ----
  #pragma unroll
  for (int i = 0; i < 4; ++i) {
    int f = tid + i * 256;          // position id, 0..1023
    *(bf16x8*)(T + (f >> 5) * CST8 + ((f & 31) << 3))
        = *(const bf16x8*)(ub + (size_t)f * 512);
  }
  // conv weights while loads are in flight
  float w00 = cw[(0 << 9) + d], w01 = cw[(1 << 9) + d], w02 = cw[(2 << 9) + d];
  float w10 = cw[(3 << 9) + d], w11 = cw[(4 << 9) + d], w12 = cw[(5 << 9) + d];
  float w20 = cw[(6 << 9) + d], w21 = cw[(7 << 9) + d], w22 = cw[(8 << 9) + d];
  const float cbv = cb[d];
  // scan bases (loop-invariant; direct expf avoids 0*inf at extreme a)
  const float A0f = expf((float)(c0 << 5) * lna),        R0f = expf((float)(c0 << 5) * -lna);
  const float A0b = expf((float)((31 - c0) << 5) * lna), R0b = expf((float)((31 - c0) << 5) * -lna);
  __syncthreads();

  // ---- phase 0: depthwise 3x3 conv + SiLU, row c0 -> Y ----
  {
    const bool up = (c0 > 0);
    const bool dn = (c0 < 31);
    float a0 = 0.f, a1 = 0.f, a2 = 0.f;                                  // col -1
    float b0 = up ? (float)T[(c0 - 1) * CST8 + ch] : 0.f;                // col 0
    float b1 =      (float)T[c0 * CST8 + ch];
    float b2 = dn ? (float)T[(c0 + 1) * CST8 + ch] : 0.f;
    #pragma unroll 4
    for (int ww = 0; ww < 32; ++ww) {
      float e0 = 0.f, e1 = 0.f, e2 = 0.f;                                // col ww+1
      if (ww < 31) {
        e0 = up ? (float)T[(c0 - 1) * CST8 + ((ww + 1) << 3) + ch] : 0.f;
        e1 =      (float)T[c0 * CST8 + ((ww + 1) << 3) + ch];
        e2 = dn ? (float)T[(c0 + 1) * CST8 + ((ww + 1) << 3) + ch] : 0.f;
      }
      float acc0 = cbv;
      acc0 = fmaf(a0, w00, acc0); acc0 = fmaf(b0, w01, acc0); acc0 = fmaf(e0, w02, acc0);
      acc0 = fmaf(a1, w10, acc0); acc0 = fmaf(b1, w11, acc0); acc0 = fmaf(e1, w12, acc0);
      acc0 = fmaf(a2, w20, acc0); acc0 = fmaf(b2, w21, acc0); acc0 = fmaf(e2, w22, acc0);
      acc0 = acc0 / (1.f + expf(-acc0));
      Y[c0 * CST8 + (ww << 3) + ch] = (__bf16)acc0;
      a0 = b0; a1 = b1; a2 = b2; b0 = e0; b1 = e1; b2 = e2;
    }
  }
  __syncthreads();

  // one scan step: r += u*bb/max(apr,1e-20) with tracked reciprocal
  #define STEP(r_, uu_, apr_, rp_)                                 \
    { float rr_ = (apr_ < 1e-20f) ? 1e20f : rp_;                   \
      r_ = fmaf((uu_) * bb, rr_, r_); }

  // ---- phase A: 4 chunk sums (rowF/rowB/colF/colB) in one loop ----
  {
    float pf = A0f, qf = R0f, pb = A0b, qb = R0b;
    float s0 = 0.f, s1 = 0.f, s2 = 0.f, s3 = 0.f;
    #pragma unroll 4
    for (int j = 0; j < 32; ++j) {
      float urf = (float)Y[c0 * CST8 + (j << 3) + ch];
      float urb = (float)Y[c0 * CST8 + ((31 - j) << 3) + ch];
      float ucf = (float)Y[j * CST8 + (c0 << 3) + ch];
      float ucb = (float)Y[(31 - j) * CST8 + (c0 << 3) + ch];
      STEP(s0, urf, pf, qf)  STEP(s2, ucf, pf, qf)
      STEP(s1, urb, pb, qb)  STEP(s3, ucb, pb, qb)
      pf *= a; qf *= ia; pb *= a; qb *= ia;
    }
    S[0][c0][ch] = s0; S[1][c0][ch] = s1; S[2][c0][ch] = s2; S[3][c0][ch] = s3;
  }
  __syncthreads();

  // ---- phase B: exclusive prefix (F arrays) / exclusive suffix (B arrays) ----
  if (tid < 32) {
    int arr = tid >> 3, ch2 = tid & 7;
    float run = 0.f;
    if ((arr & 1) == 0) {
      #pragma unroll 4
      for (int cc = 0; cc < 32; ++cc) { float v = S[arr][cc][ch2]; S[arr][cc][ch2] = run; run += v; }
    } else {
      #pragma unroll 4
      for (int cc = 31; cc >= 0; --cc) { float v = S[arr][cc][ch2]; S[arr][cc][ch2] = run; run += v; }
    }
  }
  __syncthreads();

  // ---- C-col fwd: raw partial -> T  (column c0: pos = j*32+c0 -> row j, col c0) ----
  {
    float r = S[2][c0][ch];
    float p = A0f, q = R0f;
    #pragma unroll 4
    for (int j = 0; j < 32; ++j) {
      int i0 = j * CST8 + (c0 << 3) + ch;
      float u = (float)Y[i0];
      float ap = fmaxf(p, 1e-20f);
      STEP(r, u, p, q)
      T[i0] = (__bf16)(r * ap);
      p *= a; q *= ia;
    }
  }
  // ---- C-col bwd: T = sc*(T + r*ap)  [same-thread RMW] ----
  {
    float r = S[3][c0][ch];
    float p = A0b, q = R0b;
    #pragma unroll 4
    for (int j = 31; j >= 0; --j) {
      int i0 = j * CST8 + (c0 << 3) + ch;
      float u = (float)Y[i0];
      float ap = fmaxf(p, 1e-20f);
      STEP(r, u, p, q)
      T[i0] = (__bf16)(sc * ((float)T[i0] + r * ap));
      p *= a; q *= ia;
    }
  }
  __syncthreads();   // row threads read other threads' col finals

  // ---- C-row fwd: T += sc*(r*ap)  (row c0, col j) ----
  {
    float r = S[0][c0][ch];
    float p = A0f, q = R0f;
    #pragma unroll 4
    for (int j = 0; j < 32; ++j) {
      int i0 = c0 * CST8 + (j << 3) + ch;
      float u = (float)Y[i0];
      float ap = fmaxf(p, 1e-20f);
      STEP(r, u, p, q)
      T[i0] = (__bf16)((float)T[i0] + sc * (r * ap));
      p *= a; q *= ia;
    }
  }
  // ---- C-row bwd: finalize + d*u, *gate, write out ----
  {
    const __bf16* gb = gate + ((size_t)b << 19) + (cg << 3) + ch;
    __bf16* yb = yo + ((size_t)b << 19) + (cg << 3) + ch;
    float r = S[1][c0][ch];
    float p = A0b, q = R0b;
    #pragma unroll 4
    for (int j = 31; j >= 0; --j) {
      int pp = (c0 << 5) + j;
      int i0 = c0 * CST8 + (j << 3) + ch;
      float u = (float)Y[i0];
      float ap = fmaxf(p, 1e-20f);
      STEP(r, u, p, q)
      float y0 = (float)T[i0] + sc * (r * ap) + dd * u;
      yb[(size_t)pp * 512] = (__bf16)(y0 * (float)gb[(size_t)pp * 512]);
      p *= a; q *= ia;
    }
  }
  #undef STEP
}

// ---------------- mean over 1024 positions (bf16 in) -> (16, 512) fp32 ----------------
__global__ __launch_bounds__(256) void reduce_k(const __bf16* __restrict__ hn, float* __restrict__ out)
{
  __shared__ float part[4][64];
  int l = threadIdx.x & 63;       // channel within group
  int q = threadIdx.x >> 6;       // position quarter
  int d = blockIdx.y * 64 + l;
  int b = blockIdx.x;
  const __bf16* p = hn + ((size_t)b << 19) + d + ((size_t)(q * 256) << 9);
  float s0 = 0.f, s1 = 0.f, s2 = 0.f, s3 = 0.f;
  for (int t = 0; t < 256; t += 4) {
    s0 += (float)p[(size_t)(t+0) << 9];
    s1 += (float)p[(size_t)(t+1) << 9];
    s2 += (float)p[(size_t)(t+2) << 9];
    s3 += (float)p[(size_t)(t+3) << 9];
  }
  part[q][l] = (s0 + s1) + (s2 + s3);
  __syncthreads();
  if (threadIdx.x < 64)
    out[b * 512 + d] = (part[0][l] + part[1][l] + part[2][l] + part[3][l]) * (1.f / 1024.f);
}

extern "C" void kernel_launch(void* const* d_in, const int* in_sizes, int n_in,
                              void* d_out, int out_size, void* d_ws, size_t ws_size,
                              hipStream_t stream)
{
  const float* tokens = (const float*)d_in[0];
  const float* in_w   = (const float*)d_in[1];
  const float* in_b   = (const float*)d_in[2];
  const float* nw     = (const float*)d_in[3];
  const float* nb     = (const float*)d_in[4];
  const float* iw     = (const float*)d_in[5];
  const float* ib     = (const float*)d_in[6];
  const float* cw     = (const float*)d_in[7];
  const float* cb     = (const float*)d_in[8];
  const float* al     = (const float*)d_in[9];
  const float* bbv    = (const float*)d_in[10];
  const float* ccv    = (const float*)d_in[11];
  const float* ddv    = (const float*)d_in[12];
  const float* ow     = (const float*)d_in[13];
  const float* obv    = (const float*)d_in[14];
  const float* onw    = (const float*)d_in[15];
  const float* onb    = (const float*)d_in[16];

  // workspace layout (~115 MB):
  float*  x     = (float*)d_ws;                      // fp32 residual (33.5 MB)
  __bf16* hy16  = (__bf16*)(x + PP);                 // bf16 h / yg / final-ln (16.8 MB)
  __bf16* xin16 = hy16 + PP;                         // bf16 x_in (16.8 MB)
  __bf16* g16   = xin16 + PP;                        // bf16 gate (16.8 MB)
  __bf16* iwT   = g16 + PP;                          // 4x(1024x512) bf16 (4.2 MB)
  __bf16* owT   = iwT + (size_t)4 * 1024 * 512;      // 4x(512x512) bf16 (2.1 MB)
  __bf16* tb16  = owT + (size_t)4 * 512 * 512;       // tokens bf16 (25.2 MB)
  __bf16* inwT  = xin16;                             // in_proj_w^T bf16 (pre-loop alias)

  // --- fused weight/input conversion (one dispatch) ---
  prep_k<<<9600, 256, 0, stream>>>(tokens, tb16, in_w, inwT, iw, iwT, ow, owT);

  // x = tokens @ in_proj_w + b   (128 M-tiles x 4 N-tiles = 512 blocks)
  gemm_k<<<512, 512, 0, stream>>>(tb16, inwT, in_b, nullptr, x, nullptr, nullptr,
                                  512, 768, 0);

  for (int i = 0; i < 4; ++i) {
    ln_k<<<4096, 256, 0, stream>>>(x, nw + i*512, nb + i*512, hy16);
    // (h @ iw + ib): 128 x 8 = 1024 blocks (R5-proven best)
    gemm_k<<<1024, 512, 0, stream>>>(hy16, iwT + (size_t)i*1024*512, ib + i*1024,
                                     nullptr, nullptr, g16, xin16, 1024, 512, 1);
    // 64 ch-groups x 16 batch = 1024 blocks, 4/CU
    scan2d_k<<<dim3(64, 16), 256, 0, stream>>>(xin16, cw + i*9*512, cb + i*512,
                                               al + i*512, bbv + i*512, ccv + i*512,
                                               ddv + i*512, g16, hy16);
    // (yg @ ow + ob + x): 128 x 4 = 512 blocks
    gemm_k<<<512, 512, 0, stream>>>(hy16, owT + (size_t)i*512*512, obv + i*512,
                                    x, x, nullptr, nullptr, 512, 512, 2);
  }

  ln_k<<<4096, 256, 0, stream>>>(x, onw, onb, hy16);
  reduce_k<<<dim3(16, 8), 256, 0, stream>>>(hy16, (float*)d_out);
}